// Round 15
// baseline (660.766 us; speedup 1.0000x reference)
//
#include <hip/hip_runtime.h>

#define ALPHA_F 0.1f
#define EPS_F   1e-5f

typedef float    f32x4 __attribute__((ext_vector_type(4)));
typedef _Float16 h16x8 __attribute__((ext_vector_type(8)));
typedef _Float16 h16x4 __attribute__((ext_vector_type(4)));

__device__ __forceinline__ void gll16(const void* g, void* l)
{
    __builtin_amdgcn_global_load_lds(
        (const __attribute__((address_space(1))) void*)g,
        (__attribute__((address_space(3))) void*)l, 16, 0, 0);
}

// padded count per node: self-loop + edges, rounded up to multiple of 8
__device__ __forceinline__ int pad_cnt(int d) { return (d + 8) & ~7; }

// csr entry packed in 4B: low16 = src (N < 65536), high16 = fp16 weight bits
__device__ __forceinline__ unsigned pack_csr(int s, float w)
{
    _Float16 h = (_Float16)w;
    return (unsigned)(s & 0xFFFF)
         | ((unsigned)__builtin_bit_cast(unsigned short, h) << 16);
}

// ---------------------------------------------------------------------------
// W [K x 128] fp32 -> staging-interleaved fp16 layout
// ---------------------------------------------------------------------------
__global__ void convert_wstg(const float* __restrict__ W,
                             _Float16* __restrict__ Wstg, int K)
{
    int idx = blockIdx.x * 256 + threadIdx.x;
    if (idx < K * 128) {
        int k = idx >> 7, n = idx & 127;
        int i = k >> 5, kg = (k >> 3) & 3, j = k & 7;
        Wstg[(size_t)i * 4096 + (kg * 128 + n) * 8 + j] = (_Float16)W[idx];
    }
}

// ---------------------------------------------------------------------------
// out[M,128] = BN( act(A[M,K] @ W + bias) ) — unchanged m97-style GEMM.
// ---------------------------------------------------------------------------
template<bool A_HALF, bool OUT_HALF>
__global__ __launch_bounds__(256) void gemm_stage_bn(
    const void* __restrict__ Av,
    const _Float16* __restrict__ Wstg,
    const float* __restrict__ bias,
    const float* __restrict__ gamma, const float* __restrict__ beta,
    const float* __restrict__ mean,  const float* __restrict__ var,
    void* __restrict__ outv, int M, int K, int do_relu)
{
    __shared__ __align__(16) char Abuf[2][8192];
    __shared__ __align__(16) char Wbuf[2][8192];

    const int t   = threadIdx.x;
    const int w   = t >> 6;
    const int l   = t & 63;
    const int l15 = l & 15;
    const int lk  = l >> 4;
    const int bm  = blockIdx.x * 64;
    const int nk  = K >> 5;
    const int row = w * 16 + l15;

    f32x4 acc[8];
#pragma unroll
    for (int f = 0; f < 8; ++f) acc[f] = (f32x4){0.f, 0.f, 0.f, 0.f};

    auto stage = [&](int buf, int i) {
        const char* wsrc = (const char*)Wstg + (size_t)i * 8192;
#pragma unroll
        for (int c = 0; c < 2; ++c) {
            const int base = w * 128 + c * 64;
            gll16(wsrc + (size_t)(base + l) * 16, &Wbuf[buf][base * 16]);
        }
        if (A_HALF) {
            const int base = w * 64;
            const int sl   = base + l;
            const int r    = sl >> 2;
            const int ch   = (sl & 3) ^ (r & 3);
            int gr = bm + r; gr = (gr < M) ? gr : (M - 1);
            const char* src = (const char*)Av + ((size_t)gr * K + i * 32) * 2
                              + (size_t)ch * 16;
            gll16(src, &Abuf[buf][base * 16]);
        } else {
#pragma unroll
            for (int c = 0; c < 2; ++c) {
                const int base = w * 128 + c * 64;
                const int sl   = base + l;
                const int r    = sl >> 3;
                const int ch   = (sl & 7) ^ (r & 7);
                int gr = bm + r; gr = (gr < M) ? gr : (M - 1);
                const char* src = (const char*)Av + ((size_t)gr * K + i * 32) * 4
                                  + (size_t)ch * 16;
                gll16(src, &Abuf[buf][base * 16]);
            }
        }
    };

    auto compute = [&](int buf) {
        h16x8 a;
        if (A_HALF) {
            a = *(const h16x8*)&Abuf[buf][(row * 4 + (lk ^ (row & 3))) * 16];
        } else {
            f32x4 a0 = *(const f32x4*)&Abuf[buf][(row * 8 + ((2 * lk)     ^ (row & 7))) * 16];
            f32x4 a1 = *(const f32x4*)&Abuf[buf][(row * 8 + ((2 * lk + 1) ^ (row & 7))) * 16];
#pragma unroll
            for (int j = 0; j < 4; ++j) {
                a[j]     = (_Float16)a0[j];
                a[4 + j] = (_Float16)a1[j];
            }
        }
#pragma unroll
        for (int f = 0; f < 8; ++f) {
            h16x8 b = *(const h16x8*)&Wbuf[buf][(lk * 128 + f * 16 + l15) * 16];
            acc[f] = __builtin_amdgcn_mfma_f32_16x16x32_f16(a, b, acc[f], 0, 0, 0);
        }
    };

    stage(0, 0);
    for (int i = 0; i < nk; ++i) {
        __syncthreads();
        if (i + 1 < nk) stage((i + 1) & 1, i + 1);
        compute(i & 1);
    }

#pragma unroll
    for (int f = 0; f < 8; ++f) {
        const int col = f * 16 + l15;
        float s  = gamma[col] * rsqrtf(var[col] + EPS_F);
        float sh = beta[col] - mean[col] * s;
        float bb = bias[col];
#pragma unroll
        for (int rr = 0; rr < 4; ++rr) {
            int rg = bm + w * 16 + lk * 4 + rr;
            if (rg < M) {
                float v = acc[f][rr] + bb;
                if (do_relu) v = fmaxf(v, 0.f);
                v = v * s + sh;
                if (OUT_HALF) ((_Float16*)outv)[(size_t)rg * 128 + col] = (_Float16)v;
                else          ((float*)outv)[(size_t)rg * 128 + col]    = v;
            }
        }
    }
}

// h [N][128] fp16 -> sliced [4][N][32] fp16 (64B rows per slice)
__global__ void reslice(const _Float16* __restrict__ src,
                        _Float16* __restrict__ dst, int N)
{
    int idx = blockIdx.x * 256 + threadIdx.x;   // one per 8-feat chunk
    if (idx < N * 16) {
        int i = idx >> 4;
        int f = (idx & 15) * 8;
        int s = f >> 5, wi = f & 31;
        h16x8 v = *(const h16x8*)(src + (size_t)i * 128 + f);
        *(h16x8*)(dst + ((size_t)s * N + i) * 32 + wi) = v;
    }
}

// ---------------------------------------------------------------------------
// Graph preprocessing (per launch). CSR entries are 4B {u16 src, f16 w}.
// ---------------------------------------------------------------------------
__global__ void count_deg(const int* __restrict__ dst, int E, int* __restrict__ deg)
{
    int e = blockIdx.x * 256 + threadIdx.x;
    if (e < E) atomicAdd(&deg[dst[e]], 1);
}

__global__ __launch_bounds__(256) void scan_block_sums(
    const int* __restrict__ deg, int* __restrict__ bsum, int N)
{
    __shared__ int sh[256];
    const int t  = threadIdx.x;
    const int i0 = blockIdx.x * 1024 + t * 4;
    int s = 0;
    if (i0 + 3 < N) {
        int4 d4 = *(const int4*)(deg + i0);
        s = pad_cnt(d4.x) + pad_cnt(d4.y) + pad_cnt(d4.z) + pad_cnt(d4.w);
    } else {
#pragma unroll
        for (int j = 0; j < 4; ++j)
            if (i0 + j < N) s += pad_cnt(deg[i0 + j]);
    }
    sh[t] = s;
    __syncthreads();
#pragma unroll
    for (int d = 128; d > 0; d >>= 1) {
        if (t < d) sh[t] += sh[t + d];
        __syncthreads();
    }
    if (t == 0) bsum[blockIdx.x] = sh[0];
}

__global__ __launch_bounds__(256) void scan_offsets(
    const int* __restrict__ deg, const int* __restrict__ bsum,
    int* __restrict__ offs, int* __restrict__ cursor,
    float* __restrict__ dinv, int N, int B)
{
    __shared__ int sh[256];
    __shared__ int sbase;
    const int b = blockIdx.x, t = threadIdx.x;

    int v = (t < b && t < B) ? bsum[t] : 0;
    sh[t] = v;
    __syncthreads();
#pragma unroll
    for (int d = 128; d > 0; d >>= 1) {
        if (t < d) sh[t] += sh[t + d];
        __syncthreads();
    }
    if (t == 0) sbase = sh[0];
    __syncthreads();

    const int i0 = b * 1024 + t * 4;
    int c[4], s = 0;
#pragma unroll
    for (int j = 0; j < 4; ++j) {
        int i = i0 + j;
        c[j] = (i < N) ? pad_cnt(deg[i]) : 0;
        s += c[j];
    }
    sh[t] = s;
    __syncthreads();
    for (int d = 1; d < 256; d <<= 1) {
        int o = (t >= d) ? sh[t - d] : 0;
        __syncthreads();
        sh[t] += o;
        __syncthreads();
    }
    int run = sbase + sh[t] - s;
#pragma unroll
    for (int j = 0; j < 4; ++j) {
        int i = i0 + j;
        if (i < N) {
            offs[i]   = run;
            cursor[i] = run;
            dinv[i]   = rsqrtf((float)(deg[i] + 1));
            run += c[j];
        }
    }
    if (b == B - 1 && t == 255) offs[N] = run;
}

__global__ void scatter_csr(const int* __restrict__ src, const int* __restrict__ dst,
                            int E, const float* __restrict__ dinv,
                            int* __restrict__ cursor, unsigned* __restrict__ csr4)
{
    int e = blockIdx.x * 256 + threadIdx.x;
    if (e < E) {
        int s = src[e], d = dst[e];
        int pos = atomicAdd(&cursor[d], 1);
        csr4[pos] = pack_csr(s, dinv[s] * dinv[d]);
    }
}

__global__ void fill_self_pad(const int* __restrict__ offs, const int* __restrict__ deg,
                              const float* __restrict__ dinv,
                              unsigned* __restrict__ csr4, int N)
{
    int i = blockIdx.x * 256 + threadIdx.x;
    if (i < N) {
        int base = offs[i], d = deg[i], end = offs[i + 1];
        float di = dinv[i];
        csr4[base + d] = pack_csr(i, di * di);
        for (int p = base + d + 1; p < end; ++p)
            csr4[p] = pack_csr(i, 0.f);
    }
}

// ---------------------------------------------------------------------------
// One APPNP step, FEATURE-SLICED: nxt = (1-a)*(A_hat @ cur) + a*h0.
// Features split into 4 slices of 32 (64B rows). Slice buffer = 3.2 MB
// < 4 MB per-XCD L2. slice = blockIdx.x & 3: with round-robin block->XCD
// dispatch each XCD touches exactly ONE slice -> gathers are L2-resident.
// Per edge: 8 lanes x 8B (h16x4); wave iteration = 8 edges; butterfly
// shfl_xor(8/16/32); lanes 0-7 do the epilogue. fp32 accumulation.
// ---------------------------------------------------------------------------
#define WAVES_PER_SLICE 2048

__global__ __launch_bounds__(256) void appnp_step_s(
    const _Float16* __restrict__ cur,   // [4][N][32]
    const _Float16* __restrict__ h0q,   // [4][N][32]
    const int* __restrict__ offs, const unsigned* __restrict__ csr4,
    _Float16* __restrict__ nxt, float* __restrict__ fout, int N)
{
    const int s    = blockIdx.x & 3;
    const int wis  = (blockIdx.x >> 2) * 4 + (threadIdx.x >> 6);   // 0..2047
    const int lane = (int)(threadIdx.x & 63u);
    const int q    = lane & 7;           // feat quartet (4 feats)
    const int eo   = lane >> 3;          // edge offset 0..7

    const _Float16* curs = cur + (size_t)s * N * 32;
    const _Float16* h0s  = h0q + (size_t)s * N * 32;
    _Float16*       nxts = nxt + (size_t)s * N * 32;

    for (int i = wis; i < N; i += WAVES_PER_SLICE) {
        int e   = offs[i];
        int end = offs[i + 1];

        float acc[4] = {0.f, 0.f, 0.f, 0.f};

        unsigned m = csr4[e + eo];
        h16x4 v = *(const h16x4*)(curs + (size_t)(m & 0xFFFFu) * 32 + q * 4);

        for (e += 8; e < end; e += 8) {
            unsigned m2 = csr4[e + eo];
            h16x4 v2 = *(const h16x4*)(curs + (size_t)(m2 & 0xFFFFu) * 32 + q * 4);
            float w = (float)__builtin_bit_cast(_Float16, (unsigned short)(m >> 16));
#pragma unroll
            for (int j = 0; j < 4; ++j) acc[j] = fmaf(w, (float)v[j], acc[j]);
            m = m2; v = v2;
        }
        {
            float w = (float)__builtin_bit_cast(_Float16, (unsigned short)(m >> 16));
#pragma unroll
            for (int j = 0; j < 4; ++j) acc[j] = fmaf(w, (float)v[j], acc[j]);
        }

        // combine the 8 edge-partials (lanes differing in bits 3..5)
#pragma unroll
        for (int j = 0; j < 4; ++j) {
            acc[j] += __shfl_xor(acc[j], 8);
            acc[j] += __shfl_xor(acc[j], 16);
            acc[j] += __shfl_xor(acc[j], 32);
        }

        if (lane < 8) {   // lane == q
            h16x4 hv = *(const h16x4*)(h0s + (size_t)i * 32 + q * 4);
            float o[4];
#pragma unroll
            for (int j = 0; j < 4; ++j)
                o[j] = ALPHA_F * (float)hv[j] + (1.f - ALPHA_F) * acc[j];
            if (fout) {
                f32x4 o4;
#pragma unroll
                for (int j = 0; j < 4; ++j) o4[j] = o[j];
                *(f32x4*)(fout + (size_t)i * 128 + s * 32 + q * 4) = o4;
            } else {
                h16x4 o16;
#pragma unroll
                for (int j = 0; j < 4; ++j) o16[j] = (_Float16)o[j];
                *(h16x4*)(nxts + (size_t)i * 32 + q * 4) = o16;
            }
        }
    }
}

// ---------------------------------------------------------------------------
static inline size_t align_up(size_t x) { return (x + 255) & ~(size_t)255; }

extern "C" void kernel_launch(void* const* d_in, const int* in_sizes, int n_in,
                              void* d_out, int out_size, void* d_ws, size_t ws_size,
                              hipStream_t stream)
{
    const float* x   = (const float*)d_in[0];
    const int*   ei  = (const int*)d_in[1];
    const float* W1  = (const float*)d_in[2];
    const float* b1  = (const float*)d_in[3];
    const float* g1  = (const float*)d_in[4];
    const float* be1 = (const float*)d_in[5];
    const float* m1  = (const float*)d_in[6];
    const float* v1  = (const float*)d_in[7];
    const float* W2  = (const float*)d_in[8];
    const float* b2  = (const float*)d_in[9];
    const float* g2  = (const float*)d_in[10];
    const float* be2 = (const float*)d_in[11];
    const float* m2  = (const float*)d_in[12];
    const float* v2  = (const float*)d_in[13];

    const int N = in_sizes[0] / 512;   // 50000  (< 65536: u16 src packing ok)
    const int E = in_sizes[1] / 2;     // 800000
    const int* src = ei;
    const int* dst = ei + E;
    const int CSR_CAP = E + 8 * N;     // 4B entries
    const int NB = (N + 1023) / 1024;  // 49

    char* ws = (char*)d_ws;
    size_t off = 0;
    _Float16* hAh = (_Float16*)(ws + off); off += align_up((size_t)N * 128 * 2);
    _Float16* h0h = (_Float16*)(ws + off); off += align_up((size_t)N * 128 * 2);
    _Float16* h0q = (_Float16*)(ws + off); off += align_up((size_t)N * 128 * 2);
    _Float16* q1  = (_Float16*)(ws + off); off += align_up((size_t)N * 128 * 2);
    _Float16* q2  = (_Float16*)(ws + off); off += align_up((size_t)N * 128 * 2);
    int*    deg  = (int*)(ws + off);    off += align_up((size_t)N * 4);
    float*  dinv = (float*)(ws + off);  off += align_up((size_t)N * 4);
    int*    offs = (int*)(ws + off);    off += align_up((size_t)(N + 1) * 4);
    int*    curs = (int*)(ws + off);    off += align_up((size_t)N * 4);
    int*    bsum = (int*)(ws + off);    off += align_up((size_t)256 * 4);
    unsigned* csr4 = (unsigned*)(ws + off); off += align_up((size_t)CSR_CAP * 4);
    _Float16* w1s = (_Float16*)(ws + off); off += align_up((size_t)512 * 128 * 2);
    _Float16* w2s = (_Float16*)(ws + off); off += align_up((size_t)128 * 128 * 2);

    // --- graph preprocessing ---
    hipMemsetAsync(deg, 0, (size_t)N * 4, stream);
    count_deg<<<(E + 255) / 256, 256, 0, stream>>>(dst, E, deg);
    scan_block_sums<<<NB, 256, 0, stream>>>(deg, bsum, N);
    scan_offsets<<<NB, 256, 0, stream>>>(deg, bsum, offs, curs, dinv, N, NB);
    scatter_csr<<<(E + 255) / 256, 256, 0, stream>>>(src, dst, E, dinv, curs, csr4);
    fill_self_pad<<<(N + 255) / 256, 256, 0, stream>>>(offs, deg, dinv, csr4, N);

    // --- weights -> staging-interleaved fp16 ---
    convert_wstg<<<(512 * 128 + 255) / 256, 256, 0, stream>>>(W1, w1s, 512);
    convert_wstg<<<(128 * 128 + 255) / 256, 256, 0, stream>>>(W2, w2s, 128);

    // --- MLP: hAh = BN1(relu(x@W1+b1)) fp16; h0h = BN2(hAh@W2+b2) fp16 ---
    gemm_stage_bn<false, true><<<(N + 63) / 64, 256, 0, stream>>>(
        x, w1s, b1, g1, be1, m1, v1, hAh, N, 512, 1);
    gemm_stage_bn<true, true><<<(N + 63) / 64, 256, 0, stream>>>(
        hAh, w2s, b2, g2, be2, m2, v2, h0h, N, 128, 0);

    // --- h0 -> sliced layout (initial cur AND teleport source) ---
    reslice<<<(N * 16 + 255) / 256, 256, 0, stream>>>(h0h, h0q, N);

    // --- 10 propagation steps (sliced ping-pong); step 10 writes fp32 d_out ---
    const _Float16* cur = h0q;
    for (int k = 0; k < 10; ++k) {
        _Float16* nxt = (k & 1) ? q2 : q1;
        float* fo = (k == 9) ? (float*)d_out : nullptr;
        appnp_step_s<<<WAVES_PER_SLICE * 4 / 4, 256, 0, stream>>>(
            cur, h0q, offs, csr4, nxt, fo, N);
        cur = nxt;
    }

    (void)n_in; (void)out_size; (void)ws_size;
}

// Round 16
// 404.956 us; speedup vs baseline: 1.6317x; 1.6317x over previous
//
#include <hip/hip_runtime.h>

#define ALPHA_F 0.1f
#define EPS_F   1e-5f

typedef float    f32x4 __attribute__((ext_vector_type(4)));
typedef _Float16 h16x8 __attribute__((ext_vector_type(8)));
typedef _Float16 h16x2 __attribute__((ext_vector_type(2)));

__device__ __forceinline__ void gll16(const void* g, void* l)
{
    __builtin_amdgcn_global_load_lds(
        (const __attribute__((address_space(1))) void*)g,
        (__attribute__((address_space(3))) void*)l, 16, 0, 0);
}

// padded count per node: self-loop + edges, rounded up to multiple of 8
__device__ __forceinline__ int pad_cnt(int d) { return (d + 8) & ~7; }

// csr entry packed in 4B: low16 = src (N < 65536), high16 = fp16 weight bits
// (numerically identical to R13, which converted w to fp16 before the FMA)
__device__ __forceinline__ unsigned pack_csr(int s, float w)
{
    _Float16 h = (_Float16)w;
    return (unsigned)(s & 0xFFFF)
         | ((unsigned)__builtin_bit_cast(unsigned short, h) << 16);
}

// ---------------------------------------------------------------------------
// W [K x 128] fp32 -> staging-interleaved fp16 layout (one 8 KB block per
// 32-k step; LDS reads conflict-free).
// ---------------------------------------------------------------------------
__global__ void convert_wstg(const float* __restrict__ W,
                             _Float16* __restrict__ Wstg, int K)
{
    int idx = blockIdx.x * 256 + threadIdx.x;
    if (idx < K * 128) {
        int k = idx >> 7, n = idx & 127;
        int i = k >> 5, kg = (k >> 3) & 3, j = k & 7;
        Wstg[(size_t)i * 4096 + (kg * 128 + n) * 8 + j] = (_Float16)W[idx];
    }
}

// ---------------------------------------------------------------------------
// GEMM2 (A fp16): out[M,128] = BN(A[M,K] @ W + bias) — m97-style staging.
// ---------------------------------------------------------------------------
__global__ __launch_bounds__(256) void gemm_stage_bn_h(
    const _Float16* __restrict__ Ah,
    const _Float16* __restrict__ Wstg,
    const float* __restrict__ bias,
    const float* __restrict__ gamma, const float* __restrict__ beta,
    const float* __restrict__ mean,  const float* __restrict__ var,
    _Float16* __restrict__ outh, int M, int K)
{
    __shared__ __align__(16) char Abuf[2][8192];
    __shared__ __align__(16) char Wbuf[2][8192];

    const int t   = threadIdx.x;
    const int w   = t >> 6;
    const int l   = t & 63;
    const int l15 = l & 15;
    const int lk  = l >> 4;
    const int bm  = blockIdx.x * 64;
    const int nk  = K >> 5;
    const int row = w * 16 + l15;

    f32x4 acc[8];
#pragma unroll
    for (int f = 0; f < 8; ++f) acc[f] = (f32x4){0.f, 0.f, 0.f, 0.f};

    auto stage = [&](int buf, int i) {
        const char* wsrc = (const char*)Wstg + (size_t)i * 8192;
#pragma unroll
        for (int c = 0; c < 2; ++c) {
            const int base = w * 128 + c * 64;
            gll16(wsrc + (size_t)(base + l) * 16, &Wbuf[buf][base * 16]);
        }
        const int base = w * 64;
        const int sl   = base + l;
        const int r    = sl >> 2;
        const int ch   = (sl & 3) ^ (r & 3);
        int gr = bm + r; gr = (gr < M) ? gr : (M - 1);
        const char* src = (const char*)Ah + ((size_t)gr * K + i * 32) * 2
                          + (size_t)ch * 16;
        gll16(src, &Abuf[buf][base * 16]);
    };

    auto compute = [&](int buf) {
        h16x8 a = *(const h16x8*)&Abuf[buf][(row * 4 + (lk ^ (row & 3))) * 16];
#pragma unroll
        for (int f = 0; f < 8; ++f) {
            h16x8 b = *(const h16x8*)&Wbuf[buf][(lk * 128 + f * 16 + l15) * 16];
            acc[f] = __builtin_amdgcn_mfma_f32_16x16x32_f16(a, b, acc[f], 0, 0, 0);
        }
    };

    stage(0, 0);
    for (int i = 0; i < nk; ++i) {
        __syncthreads();
        if (i + 1 < nk) stage((i + 1) & 1, i + 1);
        compute(i & 1);
    }

#pragma unroll
    for (int f = 0; f < 8; ++f) {
        const int col = f * 16 + l15;
        float s  = gamma[col] * rsqrtf(var[col] + EPS_F);
        float sh = beta[col] - mean[col] * s;
        float bb = bias[col];
#pragma unroll
        for (int rr = 0; rr < 4; ++rr) {
            int rg = bm + w * 16 + lk * 4 + rr;
            if (rg < M)
                outh[(size_t)rg * 128 + col] =
                    (_Float16)((acc[f][rr] + bb) * s + sh);
        }
    }
}

// ---------------------------------------------------------------------------
// FUSED: blocks [0,GB) = GEMM1 (A fp32, relu, out fp16); blocks [GB,..) =
// scatter_csr. Independent work overlapped in one dispatch: scatter's random
// writes hide under GEMM1's MFMA/LDS phase.
// ---------------------------------------------------------------------------
__global__ __launch_bounds__(256) void fused_gemm1_scatter(
    const float* __restrict__ Af,
    const _Float16* __restrict__ Wstg,
    const float* __restrict__ bias,
    const float* __restrict__ gamma, const float* __restrict__ beta,
    const float* __restrict__ mean,  const float* __restrict__ var,
    _Float16* __restrict__ outh, int M, int K, int GB,
    const int* __restrict__ src, const int* __restrict__ dst, int E,
    const float* __restrict__ dinv, int* __restrict__ cursor,
    unsigned* __restrict__ csr4)
{
    __shared__ __align__(16) char Abuf[2][8192];
    __shared__ __align__(16) char Wbuf[2][8192];

    if (blockIdx.x >= GB) {
        // ---- scatter branch (no barriers used) ----
        int e = (blockIdx.x - GB) * 256 + threadIdx.x;
        if (e < E) {
            int s = src[e], d = dst[e];
            int pos = atomicAdd(&cursor[d], 1);
            csr4[pos] = pack_csr(s, dinv[s] * dinv[d]);
        }
        return;
    }

    // ---- GEMM1 branch ----
    const int t   = threadIdx.x;
    const int w   = t >> 6;
    const int l   = t & 63;
    const int l15 = l & 15;
    const int lk  = l >> 4;
    const int bm  = blockIdx.x * 64;
    const int nk  = K >> 5;
    const int row = w * 16 + l15;

    f32x4 acc[8];
#pragma unroll
    for (int f = 0; f < 8; ++f) acc[f] = (f32x4){0.f, 0.f, 0.f, 0.f};

    auto stage = [&](int buf, int i) {
        const char* wsrc = (const char*)Wstg + (size_t)i * 8192;
#pragma unroll
        for (int c = 0; c < 2; ++c) {
            const int base = w * 128 + c * 64;
            gll16(wsrc + (size_t)(base + l) * 16, &Wbuf[buf][base * 16]);
        }
#pragma unroll
        for (int c = 0; c < 2; ++c) {
            const int base = w * 128 + c * 64;
            const int sl   = base + l;
            const int r    = sl >> 3;
            const int ch   = (sl & 7) ^ (r & 7);
            int gr = bm + r; gr = (gr < M) ? gr : (M - 1);
            const char* srcp = (const char*)Af + ((size_t)gr * K + i * 32) * 4
                               + (size_t)ch * 16;
            gll16(srcp, &Abuf[buf][base * 16]);
        }
    };

    auto compute = [&](int buf) {
        f32x4 a0 = *(const f32x4*)&Abuf[buf][(row * 8 + ((2 * lk)     ^ (row & 7))) * 16];
        f32x4 a1 = *(const f32x4*)&Abuf[buf][(row * 8 + ((2 * lk + 1) ^ (row & 7))) * 16];
        h16x8 a;
#pragma unroll
        for (int j = 0; j < 4; ++j) {
            a[j]     = (_Float16)a0[j];
            a[4 + j] = (_Float16)a1[j];
        }
#pragma unroll
        for (int f = 0; f < 8; ++f) {
            h16x8 b = *(const h16x8*)&Wbuf[buf][(lk * 128 + f * 16 + l15) * 16];
            acc[f] = __builtin_amdgcn_mfma_f32_16x16x32_f16(a, b, acc[f], 0, 0, 0);
        }
    };

    stage(0, 0);
    for (int i = 0; i < nk; ++i) {
        __syncthreads();
        if (i + 1 < nk) stage((i + 1) & 1, i + 1);
        compute(i & 1);
    }

#pragma unroll
    for (int f = 0; f < 8; ++f) {
        const int col = f * 16 + l15;
        float s  = gamma[col] * rsqrtf(var[col] + EPS_F);
        float sh = beta[col] - mean[col] * s;
        float bb = bias[col];
#pragma unroll
        for (int rr = 0; rr < 4; ++rr) {
            int rg = bm + w * 16 + lk * 4 + rr;
            if (rg < M) {
                float v = fmaxf(acc[f][rr] + bb, 0.f);   // relu
                outh[(size_t)rg * 128 + col] = (_Float16)(v * s + sh);
            }
        }
    }
}

// ---------------------------------------------------------------------------
// Graph preprocessing
// ---------------------------------------------------------------------------
__global__ void count_deg(const int* __restrict__ dst, int E, int* __restrict__ deg)
{
    int e = blockIdx.x * 256 + threadIdx.x;
    if (e < E) atomicAdd(&deg[dst[e]], 1);
}

__global__ __launch_bounds__(256) void scan_block_sums(
    const int* __restrict__ deg, int* __restrict__ bsum, int N)
{
    __shared__ int sh[256];
    const int t  = threadIdx.x;
    const int i0 = blockIdx.x * 1024 + t * 4;
    int s = 0;
    if (i0 + 3 < N) {
        int4 d4 = *(const int4*)(deg + i0);
        s = pad_cnt(d4.x) + pad_cnt(d4.y) + pad_cnt(d4.z) + pad_cnt(d4.w);
    } else {
#pragma unroll
        for (int j = 0; j < 4; ++j)
            if (i0 + j < N) s += pad_cnt(deg[i0 + j]);
    }
    sh[t] = s;
    __syncthreads();
#pragma unroll
    for (int d = 128; d > 0; d >>= 1) {
        if (t < d) sh[t] += sh[t + d];
        __syncthreads();
    }
    if (t == 0) bsum[blockIdx.x] = sh[0];
}

__global__ __launch_bounds__(256) void scan_offsets(
    const int* __restrict__ deg, const int* __restrict__ bsum,
    int* __restrict__ offs, int* __restrict__ cursor,
    float* __restrict__ dinv, int N, int B)
{
    __shared__ int sh[256];
    __shared__ int sbase;
    const int b = blockIdx.x, t = threadIdx.x;

    int v = (t < b && t < B) ? bsum[t] : 0;
    sh[t] = v;
    __syncthreads();
#pragma unroll
    for (int d = 128; d > 0; d >>= 1) {
        if (t < d) sh[t] += sh[t + d];
        __syncthreads();
    }
    if (t == 0) sbase = sh[0];
    __syncthreads();

    const int i0 = b * 1024 + t * 4;
    int c[4], s = 0;
#pragma unroll
    for (int j = 0; j < 4; ++j) {
        int i = i0 + j;
        c[j] = (i < N) ? pad_cnt(deg[i]) : 0;
        s += c[j];
    }
    sh[t] = s;
    __syncthreads();
    for (int d = 1; d < 256; d <<= 1) {
        int o = (t >= d) ? sh[t - d] : 0;
        __syncthreads();
        sh[t] += o;
        __syncthreads();
    }
    int run = sbase + sh[t] - s;
#pragma unroll
    for (int j = 0; j < 4; ++j) {
        int i = i0 + j;
        if (i < N) {
            offs[i]   = run;
            cursor[i] = run;
            dinv[i]   = rsqrtf((float)(deg[i] + 1));
            run += c[j];
        }
    }
    if (b == B - 1 && t == 255) offs[N] = run;
}

__global__ void fill_self_pad(const int* __restrict__ offs, const int* __restrict__ deg,
                              const float* __restrict__ dinv,
                              unsigned* __restrict__ csr4, int N)
{
    int i = blockIdx.x * 256 + threadIdx.x;
    if (i < N) {
        int base = offs[i], d = deg[i], end = offs[i + 1];
        float di = dinv[i];
        csr4[base + d] = pack_csr(i, di * di);
        for (int p = base + d + 1; p < end; ++p)
            csr4[p] = pack_csr(i, 0.f);
    }
}

// ---------------------------------------------------------------------------
// One APPNP step (fp16 features): nxt = (1-a)*(A_hat @ cur) + a*h0.
// R13 structure (best measured): persistent 8192 waves; four 16-lane groups;
// group g owns edges e+2g, e+2g+1 (metadata = one uint2/group/iter, 4B CSR);
// packed fp16 FMA; butterfly fp32 combine; step 10 writes fp32 d_out.
// ---------------------------------------------------------------------------
#define NWAVES 8192

__global__ __launch_bounds__(256) void appnp_step(
    const _Float16* __restrict__ cur, const _Float16* __restrict__ h0,
    const int* __restrict__ offs, const unsigned* __restrict__ csr4,
    _Float16* __restrict__ nxt, float* __restrict__ fout, int N)
{
    const int wv0  = __builtin_amdgcn_readfirstlane(
                        (int)((blockIdx.x * 256u + threadIdx.x) >> 6));
    const int lane = (int)(threadIdx.x & 63u);
    const int g    = lane >> 4;          // group 0..3
    const int fl   = (lane & 15) * 8;    // feature offset

    for (int i = wv0; i < N; i += NWAVES) {
        int e   = offs[i];
        int end = offs[i + 1];

        h16x2 acc[4];
#pragma unroll
        for (int j = 0; j < 4; ++j) acc[j] = (h16x2){(_Float16)0, (_Float16)0};

        // stage first 8 edges: group g owns edges e+2g, e+2g+1
        uint2 m = *(const uint2*)(csr4 + e + 2 * g);
        h16x8 vA = *(const h16x8*)(cur + (size_t)(m.x & 0xFFFFu) * 128 + fl);
        h16x8 vB = *(const h16x8*)(cur + (size_t)(m.y & 0xFFFFu) * 128 + fl);

        for (e += 8; e < end; e += 8) {
            uint2 m2 = *(const uint2*)(csr4 + e + 2 * g);
            h16x8 vA2 = *(const h16x8*)(cur + (size_t)(m2.x & 0xFFFFu) * 128 + fl);
            h16x8 vB2 = *(const h16x8*)(cur + (size_t)(m2.y & 0xFFFFu) * 128 + fl);
            _Float16 ha = __builtin_bit_cast(_Float16, (unsigned short)(m.x >> 16));
            _Float16 hb = __builtin_bit_cast(_Float16, (unsigned short)(m.y >> 16));
            h16x2 wa = (h16x2){ha, ha}, wb = (h16x2){hb, hb};
#pragma unroll
            for (int j = 0; j < 4; ++j) {
                h16x2 va = (h16x2){vA[2 * j], vA[2 * j + 1]};
                h16x2 vb = (h16x2){vB[2 * j], vB[2 * j + 1]};
                acc[j] = __builtin_elementwise_fma(wa, va, acc[j]);
                acc[j] = __builtin_elementwise_fma(wb, vb, acc[j]);
            }
            m = m2; vA = vA2; vB = vB2;
        }
        {   // tail window
            _Float16 ha = __builtin_bit_cast(_Float16, (unsigned short)(m.x >> 16));
            _Float16 hb = __builtin_bit_cast(_Float16, (unsigned short)(m.y >> 16));
            h16x2 wa = (h16x2){ha, ha}, wb = (h16x2){hb, hb};
#pragma unroll
            for (int j = 0; j < 4; ++j) {
                h16x2 va = (h16x2){vA[2 * j], vA[2 * j + 1]};
                h16x2 vb = (h16x2){vB[2 * j], vB[2 * j + 1]};
                acc[j] = __builtin_elementwise_fma(wa, va, acc[j]);
                acc[j] = __builtin_elementwise_fma(wb, vb, acc[j]);
            }
        }

        // unpack to fp32 and butterfly-combine the four group partials
        float o[8];
#pragma unroll
        for (int j = 0; j < 4; ++j) {
            o[2 * j]     = (float)acc[j][0];
            o[2 * j + 1] = (float)acc[j][1];
        }
#pragma unroll
        for (int j = 0; j < 8; ++j) {
            o[j] += __shfl_xor(o[j], 16);
            o[j] += __shfl_xor(o[j], 32);
        }

        if (lane < 16) {
            h16x8 hv = *(const h16x8*)(h0 + (size_t)i * 128 + fl);
#pragma unroll
            for (int j = 0; j < 8; ++j)
                o[j] = ALPHA_F * (float)hv[j] + (1.f - ALPHA_F) * o[j];
            if (fout) {
                f32x4 o0, o1;
#pragma unroll
                for (int j = 0; j < 4; ++j) { o0[j] = o[j]; o1[j] = o[4 + j]; }
                *(f32x4*)(fout + (size_t)i * 128 + fl)     = o0;
                *(f32x4*)(fout + (size_t)i * 128 + fl + 4) = o1;
            } else {
                h16x8 o16;
#pragma unroll
                for (int j = 0; j < 8; ++j) o16[j] = (_Float16)o[j];
                *(h16x8*)(nxt + (size_t)i * 128 + fl) = o16;
            }
        }
    }
}

// ---------------------------------------------------------------------------
static inline size_t align_up(size_t x) { return (x + 255) & ~(size_t)255; }

extern "C" void kernel_launch(void* const* d_in, const int* in_sizes, int n_in,
                              void* d_out, int out_size, void* d_ws, size_t ws_size,
                              hipStream_t stream)
{
    const float* x   = (const float*)d_in[0];
    const int*   ei  = (const int*)d_in[1];
    const float* W1  = (const float*)d_in[2];
    const float* b1  = (const float*)d_in[3];
    const float* g1  = (const float*)d_in[4];
    const float* be1 = (const float*)d_in[5];
    const float* m1  = (const float*)d_in[6];
    const float* v1  = (const float*)d_in[7];
    const float* W2  = (const float*)d_in[8];
    const float* b2  = (const float*)d_in[9];
    const float* g2  = (const float*)d_in[10];
    const float* be2 = (const float*)d_in[11];
    const float* m2  = (const float*)d_in[12];
    const float* v2  = (const float*)d_in[13];

    const int N = in_sizes[0] / 512;   // 50000  (< 65536: u16 src packing ok)
    const int E = in_sizes[1] / 2;     // 800000
    const int* src = ei;
    const int* dst = ei + E;
    const int CSR_CAP = E + 8 * N;     // 4B entries
    const int NB = (N + 1023) / 1024;  // 49
    const int GB = (N + 63) / 64;      // GEMM1 blocks (782)
    const int SB = (E + 255) / 256;    // scatter blocks (3125)

    char* ws = (char*)d_ws;
    size_t off = 0;
    _Float16* hAh = (_Float16*)(ws + off); off += align_up((size_t)N * 128 * 2);
    _Float16* h0h = (_Float16*)(ws + off); off += align_up((size_t)N * 128 * 2);
    _Float16* p0  = (_Float16*)(ws + off); off += align_up((size_t)N * 128 * 2);
    _Float16* p1  = (_Float16*)(ws + off); off += align_up((size_t)N * 128 * 2);
    int*    deg  = (int*)(ws + off);    off += align_up((size_t)N * 4);
    float*  dinv = (float*)(ws + off);  off += align_up((size_t)N * 4);
    int*    offs = (int*)(ws + off);    off += align_up((size_t)(N + 1) * 4);
    int*    curs = (int*)(ws + off);    off += align_up((size_t)N * 4);
    int*    bsum = (int*)(ws + off);    off += align_up((size_t)256 * 4);
    unsigned* csr4 = (unsigned*)(ws + off); off += align_up((size_t)CSR_CAP * 4);
    _Float16* w1s = (_Float16*)(ws + off); off += align_up((size_t)512 * 128 * 2);
    _Float16* w2s = (_Float16*)(ws + off); off += align_up((size_t)128 * 128 * 2);

    // --- graph preprocessing (degree + offsets) ---
    hipMemsetAsync(deg, 0, (size_t)N * 4, stream);
    count_deg<<<(E + 255) / 256, 256, 0, stream>>>(dst, E, deg);
    scan_block_sums<<<NB, 256, 0, stream>>>(deg, bsum, N);
    scan_offsets<<<NB, 256, 0, stream>>>(deg, bsum, offs, curs, dinv, N, NB);

    // --- weights -> staging-interleaved fp16 ---
    convert_wstg<<<(512 * 128 + 255) / 256, 256, 0, stream>>>(W1, w1s, 512);
    convert_wstg<<<(128 * 128 + 255) / 256, 256, 0, stream>>>(W2, w2s, 128);

    // --- FUSED: GEMM1 (hAh = BN1(relu(x@W1+b1)))  ||  scatter_csr ---
    fused_gemm1_scatter<<<GB + SB, 256, 0, stream>>>(
        x, w1s, b1, g1, be1, m1, v1, hAh, N, 512, GB,
        src, dst, E, dinv, curs, csr4);

    // --- self-loops + pads; GEMM2: h0h = BN2(hAh@W2+b2) ---
    fill_self_pad<<<(N + 255) / 256, 256, 0, stream>>>(offs, deg, dinv, csr4, N);
    gemm_stage_bn_h<<<GB, 256, 0, stream>>>(
        hAh, w2s, b2, g2, be2, m2, v2, h0h, N, 128);

    // --- 10 propagation steps (fp16 ping-pong); step 10 writes fp32 d_out ---
    const _Float16* cur = h0h;
    for (int k = 0; k < 10; ++k) {
        _Float16* nxt = (k & 1) ? p1 : p0;
        float* fo = (k == 9) ? (float*)d_out : nullptr;
        appnp_step<<<NWAVES / 4, 256, 0, stream>>>(
            cur, h0h, offs, csr4, nxt, fo, N);
        cur = nxt;
    }

    (void)n_in; (void)out_size; (void)ws_size;
}